// Round 2
// baseline (167.857 us; speedup 1.0000x reference)
//
#include <hip/hip_runtime.h>
#include <cmath>

// ---------------------------------------------------------------------------
// NeuralField: hashgrid encode (8 levels x 8 feats, smoothstep) + MLP
// 64 -> 256 -> 256 -> 256 -> 1 (ReLU x3, linear out), N = 262144 points.
// R14: occupancy is the lever. R13 (64f x 64p waves, TILE_M=128, 70 KB LDS,
// 2 blocks/CU) REGRESSED to 114 us: halving LDS/L2 redundancy gained nothing
// -> kernel is latency-bound on barrier-serialized phases, not
// LDS/L2-throughput-bound. R12 (105 us) had 24 waves/CU; this round returns
// to R12's proven wave shape (32 feats x 64 pts, 40 VGPR measured) and
// spends the proven in-place trick on LDS size instead:
//   - encode writes directly into bufA cols 0..63 (no bufE)
//   - layer 0 runs in-place (mid-layer barrier between last K-loop read and
//     epilogue overwrite -- mechanism proven R6/R13)
//   - fsum = dedicated 2.3 KB buffer
// LDS 43 -> 36.1 KB -> 4 blocks/CU = 32 waves/CU (HW max: 4x512 = 2048).
// __launch_bounds__(512,8) caps at 64 VGPR (40 measured in R12 -> safe).
// Spill tripwire: VGPR=64 + FETCH/WRITE >> 5 MB.
// ---------------------------------------------------------------------------

#define N_LEVELS 8
#define TABLE_PAD 8192
#define TILE_M 64
#define ACT_STRIDE 264       // shorts per activation row (256 + 8 pad)

typedef __attribute__((ext_vector_type(8))) short short8;
typedef __attribute__((ext_vector_type(16))) float float16v;

struct LevelParams {
  float scale[N_LEVELS];
  int   res[N_LEVELS];
  int   size[N_LEVELS];
};

__device__ __forceinline__ unsigned short f2bf(float f) {
  unsigned int u = __float_as_uint(f);
  u += 0x7fffu + ((u >> 16) & 1u);      // round to nearest even
  return (unsigned short)(u >> 16);
}
__device__ __forceinline__ unsigned int pack2bf(float a, float b) {
  a = a > 0.f ? a : 0.f;
  b = b > 0.f ? b : 0.f;
  return (unsigned int)f2bf(a) | ((unsigned int)f2bf(b) << 16);
}

// Pack W (K x 256 row-major f32) -> bf16 [k/16][n][k%16]: one lane's 16 B
// A-frag for 32x32x16 (feature n, k-half h8) is contiguous at n*16 + h8*8.
// Wp layout: [W0p: 4*4096][W1p: 16*4096][W2p: 16*4096] shorts.
__global__ void pack_weights_kernel(const float* __restrict__ W0,
                                    const float* __restrict__ W1,
                                    const float* __restrict__ W2,
                                    unsigned short* __restrict__ Wp) {
  int tid = blockIdx.x * blockDim.x + threadIdx.x;
  const float* src;
  int base, e;
  if (tid < 16384)        { src = W0; base = 0;     e = tid;         }
  else if (tid < 81920)   { src = W1; base = 16384; e = tid - 16384; }
  else if (tid < 147456)  { src = W2; base = 81920; e = tid - 81920; }
  else return;
  int ki = e & 15;
  int n  = (e >> 4) & 255;
  int kb = e >> 12;
  unsigned int u = __float_as_uint(src[(kb * 16 + ki) * 256 + n]);
  u += 0x7fffu + ((u >> 16) & 1u);
  Wp[base + e] = (unsigned short)(u >> 16);
}

__global__ __launch_bounds__(512, 8) void neural_field_kernel(
    const float* __restrict__ x,
    const float* __restrict__ table,
    const unsigned short* __restrict__ Wp,
    const float* __restrict__ W3,
    float* __restrict__ out,
    LevelParams P) {
  // ONE activation buffer, data stored [point m][feature k]. Encode output
  // lives in cols 0..63; every layer reads what it needs, hits the mid-layer
  // barrier, then overwrites in place.
  __shared__ unsigned short bufA[TILE_M * ACT_STRIDE];   // 33792 B
  __shared__ float fsum[TILE_M * 9];                     //  2304 B

  const int t  = threadIdx.x;
  const int g0 = blockIdx.x * TILE_M;

  const int lane  = t & 63;
  const int w     = t >> 6;       // 0..7
  const int l31   = lane & 31;
  const int h8    = lane >> 5;    // 0/1: k-half within a 16-k step
  const int wbase = w * 32;       // this wave's 32 OUTPUT FEATURES

  // Per-wave weight A-frag base offset (elements) in a layer's packed W.
  const int woff = (wbase + l31) * 16 + h8 * 8;

  // ------------- Phase 1: hashgrid encode, 1 level/thread -> bufA ---------
  {
    int p = t & 63;        // point within tile
    int l = t >> 6;        // level 0..7
    float2 xy = ((const float2*)x)[g0 + p];
    float scale = P.scale[l];
    int res = P.res[l], size = P.size[l];
    float posx = xy.x * scale + 0.5f;
    float posy = xy.y * scale + 0.5f;
    float pgx = floorf(posx), pgy = floorf(posy);
    float fx = posx - pgx, fy = posy - pgy;
    float wx = fx * fx * (3.0f - 2.0f * fx);
    float wy = fy * fy * (3.0f - 2.0f * fy);
    int px = (int)pgx, py = (int)pgy;
    float acc[8] = {0, 0, 0, 0, 0, 0, 0, 0};
    for (int dy = 0; dy < 2; ++dy) {
      float wyv = dy ? wy : 1.0f - wy;
      for (int dx = 0; dx < 2; ++dx) {
        float wgt = (dx ? wx : 1.0f - wx) * wyv;
        int idx = (px + dx) + (py + dy) * res;
        if (idx >= size) idx -= size;   // idx < 2*size always
        const float4* tp =
            (const float4*)(table + ((size_t)l * TABLE_PAD + idx) * 8);
        float4 t0 = tp[0], t1 = tp[1];
        acc[0] += wgt * t0.x; acc[1] += wgt * t0.y;
        acc[2] += wgt * t0.z; acc[3] += wgt * t0.w;
        acc[4] += wgt * t1.x; acc[5] += wgt * t1.y;
        acc[6] += wgt * t1.z; acc[7] += wgt * t1.w;
      }
    }
    union { unsigned short s[8]; short8 v; } u;
    for (int j = 0; j < 8; ++j) u.s[j] = f2bf(acc[j]);
    *(short8*)&bufA[p * ACT_STRIDE + l * 8] = u.v;
  }

  // ---- MFMA layer (transposed, 32x32x16): D = W^T[32 x K] @ X^T[K x 64] --
  // A-frag (weights): row n = wbase+l31, k = kb*16 + h8*8 + j   (from L2).
  // B-frag (acts):    col m = pt*32+l31, k = kb*16 + h8*8 + j   (from LDS).
  // D: col m = pt*32+l31; reg 4q+r -> n = wbase + 8q + 4h8 + r.
  // inplace: barrier between last K-loop read and the epilogue overwrite.
  // fuse_final: dot acc with W3 in registers instead of writing acts.
  auto run_layer = [&](const unsigned short* Wpl, int KB, short8 wf0,
                       bool inplace, bool fuse_final) {
    float16v acc[2];
#pragma unroll
    for (int j = 0; j < 16; ++j) { acc[0][j] = 0.f; acc[1][j] = 0.f; }

    const unsigned short* ap0 = &bufA[l31 * ACT_STRIDE + h8 * 8];
    const unsigned short* ap1 = ap0 + 32 * ACT_STRIDE;
    const unsigned short* wp  = Wpl + woff;

    short8 af0[2];
    af0[0] = *(const short8*)(ap0);
    af0[1] = *(const short8*)(ap1);

#pragma unroll
    for (int kb = 0; kb < KB; ++kb) {
      short8 wf1, af1[2];
      int kn = (kb + 1 < KB) ? kb + 1 : kb;
      wf1    = *(const short8*)(wp + kn * 4096);
      af1[0] = *(const short8*)(ap0 + kn * 16);
      af1[1] = *(const short8*)(ap1 + kn * 16);

      acc[0] = __builtin_amdgcn_mfma_f32_32x32x16_bf16(wf0, af0[0], acc[0],
                                                       0, 0, 0);
      acc[1] = __builtin_amdgcn_mfma_f32_32x32x16_bf16(wf0, af0[1], acc[1],
                                                       0, 0, 0);
      wf0 = wf1; af0[0] = af1[0]; af0[1] = af1[1];
    }

    if (inplace) __syncthreads();   // all K-loop reads done before overwrite

    if (!fuse_final) {
      // Epilogue: ReLU + bf16 pack; 4 b64 writes per pt-tile, already in
      // the next layer's [m][k-contiguous] layout.
#pragma unroll
      for (int pt = 0; pt < 2; ++pt) {
        int m = pt * 32 + l31;
#pragma unroll
        for (int q = 0; q < 4; ++q) {
          int n0 = wbase + 8 * q + 4 * h8;
          uint2 pk;
          pk.x = pack2bf(acc[pt][4 * q + 0], acc[pt][4 * q + 1]);
          pk.y = pack2bf(acc[pt][4 * q + 2], acc[pt][4 * q + 3]);
          *(uint2*)&bufA[m * ACT_STRIDE + n0] = pk;
        }
      }
    } else {
      // Fused final layer: per-lane relu-dot over this wave's 32 features
      // (16 per k-half, W3 loaded after the K-loop), combine halves via
      // shfl_xor(32), stage per-wave partials to fsum[m*9 + w].
      float part0 = 0.f, part1 = 0.f;
#pragma unroll
      for (int q = 0; q < 4; ++q) {
        float4 wv = *(const float4*)(W3 + wbase + 8 * q + 4 * h8);
        float w3v[4] = {wv.x, wv.y, wv.z, wv.w};
#pragma unroll
        for (int r = 0; r < 4; ++r) {
          float v0 = acc[0][4 * q + r]; v0 = v0 > 0.f ? v0 : 0.f;
          float v1 = acc[1][4 * q + r]; v1 = v1 > 0.f ? v1 : 0.f;
          part0 += v0 * w3v[r];
          part1 += v1 * w3v[r];
        }
      }
      part0 += __shfl_xor(part0, 32);
      part1 += __shfl_xor(part1, 32);
      float val = h8 ? part1 : part0;   // lane holds m = h8*32 + l31 = lane
      fsum[lane * 9 + w] = val;
    }
  };

  short8 wf = *(const short8*)(Wp + woff);          // L0 wf preload
  __syncthreads();
  // Layer 0: reads cols 0..63 (K=64), overwrites cols 0..255 IN-PLACE
  run_layer(Wp, 4, wf, true, false);
  wf = *(const short8*)(Wp + 16384 + woff);         // L1 wf preload
  __syncthreads();
  // Layer 1: bufA -> bufA IN-PLACE (mid-layer barrier inside)
  run_layer(Wp + 16384, 16, wf, true, false);
  wf = *(const short8*)(Wp + 81920 + woff);         // L2 wf preload
  __syncthreads();
  // Layer 2 + final: reads bufA, writes only fsum (disjoint buffer)
  run_layer(Wp + 81920, 16, wf, false, true);
  __syncthreads();

  // ---------------- Cross-wave reduce of fsum -> out -----------------------
  {
    int p = t >> 3;          // point within tile (0..63)
    int q = t & 7;           // wave index being summed
    float v = fsum[p * 9 + q];
    v += __shfl_xor(v, 1);
    v += __shfl_xor(v, 2);
    v += __shfl_xor(v, 4);
    if (q == 0) out[g0 + p] = v;
  }
}

extern "C" void kernel_launch(void* const* d_in, const int* in_sizes, int n_in,
                              void* d_out, int out_size, void* d_ws,
                              size_t ws_size, hipStream_t stream) {
  const float* x     = (const float*)d_in[0];
  const float* table = (const float*)d_in[1];
  const float* W0    = (const float*)d_in[2];
  const float* W1    = (const float*)d_in[3];
  const float* W2    = (const float*)d_in[4];
  const float* W3    = (const float*)d_in[5];
  float* out = (float*)d_out;
  int N = in_sizes[0] / 2;

  unsigned short* Wp = (unsigned short*)d_ws;   // 147456 bf16 = 288 KB

  // Level params, double precision to match the Python reference exactly.
  LevelParams P;
  const double c = 1.2599210739135742;
  double m = 1.0;
  for (int l = 0; l < N_LEVELS; ++l) {
    double scale_d = 16.0 * m - 1.0;
    int res = (int)std::ceil(scale_d) + 1;
    long long sz = ((long long)res * res + 7) / 8 * 8;
    if (sz > (1LL << 19)) sz = 1LL << 19;
    P.scale[l] = (float)scale_d;
    P.res[l]   = res;
    P.size[l]  = (int)sz;
    m *= c;
  }

  hipLaunchKernelGGL(pack_weights_kernel, dim3(576), dim3(256), 0, stream,
                     W0, W1, W2, Wp);
  hipLaunchKernelGGL(neural_field_kernel, dim3(N / TILE_M), dim3(512), 0,
                     stream, x, table, Wp, W3, out, P);
}

// Round 4
// 162.829 us; speedup vs baseline: 1.0309x; 1.0309x over previous
//
#include <hip/hip_runtime.h>
#include <cmath>

// ---------------------------------------------------------------------------
// NeuralField: hashgrid encode (8 levels x 8 feats, smoothstep) + MLP
// 64 -> 256 -> 256 -> 256 -> 1 (ReLU x3, linear out), N = 262144 points.
// R15 (resubmit; R3 bench was GPUAcquisitionTimeout — never ran).
// Barrier semantics: R12(24w)=105, R13(16w, half LDS traffic)=114,
// R14(32w, +spill)=112 => neither occupancy nor LDS/L2 throughput is the
// limiter; kernel is in a phase-sum regime (lockstep waves use pipes
// sequentially) and every __syncthreads drains vmcnt(0), exposing L2
// weight latency to all waves at once at each layer boundary (m97
// mechanism). Changes vs R14:
//   - ALL __syncthreads -> raw s_barrier + lgkmcnt(0)-only waits
//     (vmcnt NEVER drained at barriers), memory-clobber fenced.
//   - next-layer weight frag issued BEFORE the K-loop's final MFMAs,
//     stays in flight across epilogue + 2 barriers (~300 cyc cover).
//   - K-loop tail peeled (no dummy reads).
//   - __launch_bounds__(512,6): 85-reg cap, kills R14's scratch spill
//     (WRITE_SIZE 13.5 MB tripwire -> expect ~1 MB). 3 blocks/CU.
// Correctness: read-before-overwrite needs only program-order MFMA
// consumption + s_barrier; write-before-read needs lgkmcnt(0)+s_barrier.
// ---------------------------------------------------------------------------

#define N_LEVELS 8
#define TABLE_PAD 8192
#define TILE_M 64
#define ACT_STRIDE 264       // shorts per activation row (256 + 8 pad)

typedef __attribute__((ext_vector_type(8))) short short8;
typedef __attribute__((ext_vector_type(16))) float float16v;

// lgkm-only drain (keeps global loads in flight), compiler memory fence.
#define LGKM0() asm volatile("s_waitcnt lgkmcnt(0)" ::: "memory")
// keep LDS ops from moving across the barrier at compile time
#define CFENCE() asm volatile("" ::: "memory")

struct LevelParams {
  float scale[N_LEVELS];
  int   res[N_LEVELS];
  int   size[N_LEVELS];
};

__device__ __forceinline__ unsigned short f2bf(float f) {
  unsigned int u = __float_as_uint(f);
  u += 0x7fffu + ((u >> 16) & 1u);      // round to nearest even
  return (unsigned short)(u >> 16);
}
__device__ __forceinline__ unsigned int pack2bf(float a, float b) {
  a = a > 0.f ? a : 0.f;
  b = b > 0.f ? b : 0.f;
  return (unsigned int)f2bf(a) | ((unsigned int)f2bf(b) << 16);
}

// Pack W (K x 256 row-major f32) -> bf16 [k/16][n][k%16]: one lane's 16 B
// A-frag for 32x32x16 (feature n, k-half h8) is contiguous at n*16 + h8*8.
// Wp layout: [W0p: 4*4096][W1p: 16*4096][W2p: 16*4096] shorts.
__global__ void pack_weights_kernel(const float* __restrict__ W0,
                                    const float* __restrict__ W1,
                                    const float* __restrict__ W2,
                                    unsigned short* __restrict__ Wp) {
  int tid = blockIdx.x * blockDim.x + threadIdx.x;
  const float* src;
  int base, e;
  if (tid < 16384)        { src = W0; base = 0;     e = tid;         }
  else if (tid < 81920)   { src = W1; base = 16384; e = tid - 16384; }
  else if (tid < 147456)  { src = W2; base = 81920; e = tid - 81920; }
  else return;
  int ki = e & 15;
  int n  = (e >> 4) & 255;
  int kb = e >> 12;
  unsigned int u = __float_as_uint(src[(kb * 16 + ki) * 256 + n]);
  u += 0x7fffu + ((u >> 16) & 1u);
  Wp[base + e] = (unsigned short)(u >> 16);
}

__global__ __launch_bounds__(512, 6) void neural_field_kernel(
    const float* __restrict__ x,
    const float* __restrict__ table,
    const unsigned short* __restrict__ Wp,
    const float* __restrict__ W3,
    float* __restrict__ out,
    LevelParams P) {
  // ONE activation buffer, [point m][feature k]. Encode output in cols
  // 0..63; every layer reads what it needs, mid-layer barrier, overwrites.
  __shared__ unsigned short bufA[TILE_M * ACT_STRIDE];   // 33792 B
  __shared__ float fsum[TILE_M * 9];                     //  2304 B

  const int t  = threadIdx.x;
  const int g0 = blockIdx.x * TILE_M;

  const int lane  = t & 63;
  const int w     = t >> 6;       // 0..7
  const int l31   = lane & 31;
  const int h8    = lane >> 5;    // 0/1: k-half within a 16-k step
  const int wbase = w * 32;       // this wave's 32 OUTPUT FEATURES

  // Per-wave weight A-frag base offset (elements) in a layer's packed W.
  const int woff = (wbase + l31) * 16 + h8 * 8;

  // L0 first weight frag: issue at kernel top; encode's own vmcnt waits
  // drain it for free long before L0 needs it.
  short8 wf = *(const short8*)(Wp + woff);

  // ------------- Phase 1: hashgrid encode, 1 level/thread -> bufA ---------
  {
    int p = t & 63;        // point within tile
    int l = t >> 6;        // level 0..7
    float2 xy = ((const float2*)x)[g0 + p];
    float scale = P.scale[l];
    int res = P.res[l], size = P.size[l];
    float posx = xy.x * scale + 0.5f;
    float posy = xy.y * scale + 0.5f;
    float pgx = floorf(posx), pgy = floorf(posy);
    float fx = posx - pgx, fy = posy - pgy;
    float wx = fx * fx * (3.0f - 2.0f * fx);
    float wy = fy * fy * (3.0f - 2.0f * fy);
    int px = (int)pgx, py = (int)pgy;
    float acc[8] = {0, 0, 0, 0, 0, 0, 0, 0};
    for (int dy = 0; dy < 2; ++dy) {
      float wyv = dy ? wy : 1.0f - wy;
      for (int dx = 0; dx < 2; ++dx) {
        float wgt = (dx ? wx : 1.0f - wx) * wyv;
        int idx = (px + dx) + (py + dy) * res;
        if (idx >= size) idx -= size;   // idx < 2*size always
        const float4* tp =
            (const float4*)(table + ((size_t)l * TABLE_PAD + idx) * 8);
        float4 t0 = tp[0], t1 = tp[1];
        acc[0] += wgt * t0.x; acc[1] += wgt * t0.y;
        acc[2] += wgt * t0.z; acc[3] += wgt * t0.w;
        acc[4] += wgt * t1.x; acc[5] += wgt * t1.y;
        acc[6] += wgt * t1.z; acc[7] += wgt * t1.w;
      }
    }
    union { unsigned short s[8]; short8 v; } u;
    for (int j = 0; j < 8; ++j) u.s[j] = f2bf(acc[j]);
    *(short8*)&bufA[p * ACT_STRIDE + l * 8] = u.v;
  }

  LGKM0();                          // encode ds_writes complete
  __builtin_amdgcn_s_barrier();
  CFENCE();

  // ---- MFMA layer (transposed, 32x32x16): D = W^T[32 x K] @ X^T[K x 64] --
  // A-frag (weights): row n = wbase+l31, k = kb*16 + h8*8 + j   (from L2).
  // B-frag (acts):    col m = pt*32+l31, k = kb*16 + h8*8 + j   (from LDS).
  // D: col m = pt*32+l31; reg 4q+r -> n = wbase + 8q + 4h8 + r.
  // inplace: raw barrier between last K-loop read and epilogue overwrite.
  // WpNext: next layer's first weight frag, issued before final MFMAs so it
  // flies across the epilogue + 2 barriers (vmcnt NOT drained there).
  auto run_layer = [&](const unsigned short* Wpl, int KB, short8 wf0,
                       bool inplace, bool fuse_final,
                       const unsigned short* WpNext) -> short8 {
    float16v acc[2];
#pragma unroll
    for (int j = 0; j < 16; ++j) { acc[0][j] = 0.f; acc[1][j] = 0.f; }

    const unsigned short* ap0 = &bufA[l31 * ACT_STRIDE + h8 * 8];
    const unsigned short* ap1 = ap0 + 32 * ACT_STRIDE;
    const unsigned short* wp  = Wpl + woff;

    short8 a0 = *(const short8*)(ap0);
    short8 a1 = *(const short8*)(ap1);

#pragma unroll
    for (int kb = 0; kb < KB - 1; ++kb) {
      short8 wn = *(const short8*)(wp + (kb + 1) * 4096);
      short8 b0 = *(const short8*)(ap0 + (kb + 1) * 16);
      short8 b1 = *(const short8*)(ap1 + (kb + 1) * 16);
      acc[0] = __builtin_amdgcn_mfma_f32_32x32x16_bf16(wf0, a0, acc[0],
                                                       0, 0, 0);
      acc[1] = __builtin_amdgcn_mfma_f32_32x32x16_bf16(wf0, a1, acc[1],
                                                       0, 0, 0);
      wf0 = wn; a0 = b0; a1 = b1;
    }
    short8 wnext{};
    if (WpNext) wnext = *(const short8*)(WpNext + woff);   // cross-barrier
    acc[0] = __builtin_amdgcn_mfma_f32_32x32x16_bf16(wf0, a0, acc[0],
                                                     0, 0, 0);
    acc[1] = __builtin_amdgcn_mfma_f32_32x32x16_bf16(wf0, a1, acc[1],
                                                     0, 0, 0);

    if (inplace) {
      // All waves' ds_reads are consumed by MFMAs above (compiler lgkm
      // waits precede issue); raw barrier suffices for read-before-write.
      __builtin_amdgcn_s_barrier();
      CFENCE();
    }

    if (!fuse_final) {
      // Epilogue: ReLU + bf16 pack; 4 b64 writes per pt-tile, already in
      // the next layer's [m][k-contiguous] layout.
#pragma unroll
      for (int pt = 0; pt < 2; ++pt) {
        int m = pt * 32 + l31;
#pragma unroll
        for (int q = 0; q < 4; ++q) {
          int n0 = wbase + 8 * q + 4 * h8;
          uint2 pk;
          pk.x = pack2bf(acc[pt][4 * q + 0], acc[pt][4 * q + 1]);
          pk.y = pack2bf(acc[pt][4 * q + 2], acc[pt][4 * q + 3]);
          *(uint2*)&bufA[m * ACT_STRIDE + n0] = pk;
        }
      }
    } else {
      // Fused final layer: per-lane relu-dot over this wave's 32 features
      // (16 per k-half, W3 loaded after the K-loop), combine halves via
      // shfl_xor(32), stage per-wave partials to fsum[m*9 + w].
      float part0 = 0.f, part1 = 0.f;
#pragma unroll
      for (int q = 0; q < 4; ++q) {
        float4 wv = *(const float4*)(W3 + wbase + 8 * q + 4 * h8);
        float w3v[4] = {wv.x, wv.y, wv.z, wv.w};
#pragma unroll
        for (int r = 0; r < 4; ++r) {
          float v0 = acc[0][4 * q + r]; v0 = v0 > 0.f ? v0 : 0.f;
          float v1 = acc[1][4 * q + r]; v1 = v1 > 0.f ? v1 : 0.f;
          part0 += v0 * w3v[r];
          part1 += v1 * w3v[r];
        }
      }
      part0 += __shfl_xor(part0, 32);
      part1 += __shfl_xor(part1, 32);
      float val = h8 ? part1 : part0;   // lane holds m = h8*32 + l31 = lane
      fsum[lane * 9 + w] = val;
    }
    return wnext;
  };

  // Layer 0: reads cols 0..63 (K=64), overwrites cols 0..255 IN-PLACE
  wf = run_layer(Wp, 4, wf, true, false, Wp + 16384);
  LGKM0();                          // epilogue ds_writes complete
  __builtin_amdgcn_s_barrier();
  CFENCE();
  // Layer 1: bufA -> bufA IN-PLACE (raw mid-layer barrier inside)
  wf = run_layer(Wp + 16384, 16, wf, true, false, Wp + 81920);
  LGKM0();
  __builtin_amdgcn_s_barrier();
  CFENCE();
  // Layer 2 + final: reads bufA, writes only fsum (disjoint buffer)
  run_layer(Wp + 81920, 16, wf, false, true, nullptr);
  LGKM0();                          // fsum writes complete
  __builtin_amdgcn_s_barrier();
  CFENCE();

  // ---------------- Cross-wave reduce of fsum -> out -----------------------
  {
    int p = t >> 3;          // point within tile (0..63)
    int q = t & 7;           // wave index being summed
    float v = fsum[p * 9 + q];
    v += __shfl_xor(v, 1);
    v += __shfl_xor(v, 2);
    v += __shfl_xor(v, 4);
    if (q == 0) out[g0 + p] = v;
  }
}

extern "C" void kernel_launch(void* const* d_in, const int* in_sizes, int n_in,
                              void* d_out, int out_size, void* d_ws,
                              size_t ws_size, hipStream_t stream) {
  const float* x     = (const float*)d_in[0];
  const float* table = (const float*)d_in[1];
  const float* W0    = (const float*)d_in[2];
  const float* W1    = (const float*)d_in[3];
  const float* W2    = (const float*)d_in[4];
  const float* W3    = (const float*)d_in[5];
  float* out = (float*)d_out;
  int N = in_sizes[0] / 2;

  unsigned short* Wp = (unsigned short*)d_ws;   // 147456 bf16 = 288 KB

  // Level params, double precision to match the Python reference exactly.
  LevelParams P;
  const double c = 1.2599210739135742;
  double m = 1.0;
  for (int l = 0; l < N_LEVELS; ++l) {
    double scale_d = 16.0 * m - 1.0;
    int res = (int)std::ceil(scale_d) + 1;
    long long sz = ((long long)res * res + 7) / 8 * 8;
    if (sz > (1LL << 19)) sz = 1LL << 19;
    P.scale[l] = (float)scale_d;
    P.res[l]   = res;
    P.size[l]  = (int)sz;
    m *= c;
  }

  hipLaunchKernelGGL(pack_weights_kernel, dim3(576), dim3(256), 0, stream,
                     W0, W1, W2, Wp);
  hipLaunchKernelGGL(neural_field_kernel, dim3(N / TILE_M), dim3(512), 0,
                     stream, x, table, Wp, W3, out, P);
}